// Round 2
// baseline (463.597 us; speedup 1.0000x reference)
//
#include <hip/hip_runtime.h>

// Problem: B=2048, C=16, S=2000, fp32.
// Reference collapses: softmax rows sum to 1 => attention branch multiplies
// x by 1.0 (+-1e-7). out = LN_c(Wp @ x[b,:,s] + bp)*gp + hp.
// Memory-bound: 262 MB in + 262 MB out -> ~83 us floor @ 6.3 TB/s.
//
// R1 change: W/b/g/h are wave-uniform -> read from global with unrolled
// constant indices so they scalarize to s_load (SGPR operand in v_fmac),
// removing 256 ds_read_b32/thread + lgkmcnt waits + barrier of the LDS
// staging version. Vector-typed math for v_pk_fma_f32; nontemporal stores.

typedef float v4f __attribute__((ext_vector_type(4)));

#define NC 16          // channels
#define NS 2000        // sequence
#define SV (NS / 4)    // 500 float4 per (b,c) row
#define EPS 1e-5f
#define BLK 256

__global__ __launch_bounds__(BLK) void chanattn_fused(
    const float* __restrict__ x,
    const float* __restrict__ Wp,
    const float* __restrict__ bp,
    const float* __restrict__ gp,
    const float* __restrict__ hp,
    float* __restrict__ out,
    unsigned total)        // B * SV = 1,024,000 (grid tiles exactly)
{
    const unsigned t = blockIdx.x * BLK + threadIdx.x;
    if (t >= total) return;
    const unsigned b  = t / SV;        // const-div -> magic mul
    const unsigned s4 = t - b * SV;

    const v4f* __restrict__ px = (const v4f*)x   + (size_t)b * (NC * SV) + s4;
    v4f*       __restrict__ po = (v4f*)out       + (size_t)b * (NC * SV) + s4;

    // 16 independent coalesced 16B/lane loads in flight per wave.
    v4f xv[NC];
#pragma unroll
    for (int c = 0; c < NC; ++c) xv[c] = px[c * SV];

    // y[c] = bp[c] + sum_cp Wp[c][cp] * x[cp], 4 positions at once.
    // W reads: wave-uniform address, unrolled-constant index -> s_load.
    const v4f* __restrict__ W4 = (const v4f*)Wp;   // W4[c*4+j] = Wp[c][4j..4j+3]
    v4f y[NC];
#pragma unroll
    for (int c = 0; c < NC; ++c) {
        v4f acc = bp[c];               // scalar splat (uniform -> s_load)
#pragma unroll
        for (int j = 0; j < 4; ++j) {
            const v4f w = W4[c * 4 + j];
            acc = w[0] * xv[4 * j + 0] + acc;   // contracts to fma (hip default)
            acc = w[1] * xv[4 * j + 1] + acc;
            acc = w[2] * xv[4 * j + 2] + acc;
            acc = w[3] * xv[4 * j + 3] + acc;
        }
        y[c] = acc;
    }

    // LayerNorm over the 16 channels, per position, in registers.
    const float inv = 1.0f / NC;
    v4f s = 0.0f;
#pragma unroll
    for (int c = 0; c < NC; ++c) s += y[c];
    const v4f mu = s * inv;

    v4f var = 0.0f;
#pragma unroll
    for (int c = 0; c < NC; ++c) {
        const v4f d = y[c] - mu;
        var = d * d + var;
    }
    v4f r;
    r[0] = rsqrtf(var[0] * inv + EPS);
    r[1] = rsqrtf(var[1] * inv + EPS);
    r[2] = rsqrtf(var[2] * inv + EPS);
    r[3] = rsqrtf(var[3] * inv + EPS);

#pragma unroll
    for (int c = 0; c < NC; ++c) {
        const v4f o = (y[c] - mu) * r * gp[c] + hp[c];
        __builtin_nontemporal_store(o, po + c * SV);
    }
}

extern "C" void kernel_launch(void* const* d_in, const int* in_sizes, int n_in,
                              void* d_out, int out_size, void* d_ws, size_t ws_size,
                              hipStream_t stream) {
    // setup_inputs order: x, Wq, bq, gq, hq, Wk, bk, gk, hk, Wp, bp, gp, hp
    const float* x  = (const float*)d_in[0];
    const float* Wp = (const float*)d_in[9];
    const float* bp = (const float*)d_in[10];
    const float* gp = (const float*)d_in[11];
    const float* hp = (const float*)d_in[12];
    float* out = (float*)d_out;

    const unsigned B = (unsigned)(in_sizes[0] / (NC * NS));  // 2048
    const unsigned total = B * SV;                            // 1,024,000
    const unsigned grid = (total + BLK - 1) / BLK;            // 4000, exact
    chanattn_fused<<<grid, BLK, 0, stream>>>(x, Wp, bp, gp, hp, out, total);
}